// Round 9
// baseline (233.648 us; speedup 1.0000x reference)
//
#include <hip/hip_runtime.h>

// Sparsemax, d=1024, 32768 rows, fp32 — DEPTH-3 sustained-outstanding pipeline.
// R0-R8: ten structures, all 75-90us, HBM ~2.5TB/s, VALU 22-36%. Dead
// theories: ILP, sw-pipelining, NT stores, rw-mix, 2-pass, load latency,
// VALU volume (weak), lockstep rows, queue oversubscription. Surviving
// observation: every variant time-averaged ~25-30KB of outstanding reads
// per CU (Little's law -> the measured 2.5TB/s at ~3us loaded latency);
// R8's depth-2 pipeline absorbs only ~1 solve-phase of latency. This
// round sustains 12KB reads + 8KB stores in flight PER WAVE (depth-3
// LDS-DMA rotation) x 12 waves/CU (768 blocks x 4 waves; 48KB LDS pins
// exactly 3 blocks/CU) = ~5x the outstanding depth of any prior round.
// vmcnt schedule (in-order retire, 4 DMA + 4 stores per iter):
//   prologue waits 8 / 12 / 16, steady-state 20, epilogue 20 / 16 / 12
// each draining exactly the oldest row's 4-op DMA group, never stores.
// Solve per row (R6, cheapest known): per-lane top-4-of-16 sorting
// network -> exact 4-elem Newton  t' = t + (S(t)-1)/C(t), t0 = max-1
// (monotone from below, ~5-8 iters); whole-wave fallback to the full
// 16-elem path if any lane's 4th-largest > max-1 (ballot, rare).
// rcp not divide (C exact small int; final step -> 0; tau err ~1e-7).

#define ROW_D 1024

typedef float f4 __attribute__((ext_vector_type(4)));

template <int CTRL, int RMASK>
__device__ __forceinline__ float dpp_mv(float x) {
    return __builtin_bit_cast(float, __builtin_amdgcn_update_dpp(
        __builtin_bit_cast(int, x), __builtin_bit_cast(int, x),
        CTRL, RMASK, 0xf, false));
}

__device__ __forceinline__ float dpp_sum_to63(float x) {
    x += dpp_mv<0x111, 0xf>(x);   // row_shr:1
    x += dpp_mv<0x112, 0xf>(x);   // row_shr:2
    x += dpp_mv<0x114, 0xf>(x);   // row_shr:4
    x += dpp_mv<0x118, 0xf>(x);   // row_shr:8
    x += dpp_mv<0x142, 0xa>(x);   // row_bcast15 -> rows 1,3
    x += dpp_mv<0x143, 0xc>(x);   // row_bcast31 -> rows 2,3
    return x;
}
__device__ __forceinline__ float dpp_max_to63(float x) {
    x = fmaxf(x, dpp_mv<0x111, 0xf>(x));
    x = fmaxf(x, dpp_mv<0x112, 0xf>(x));
    x = fmaxf(x, dpp_mv<0x114, 0xf>(x));
    x = fmaxf(x, dpp_mv<0x118, 0xf>(x));
    x = fmaxf(x, dpp_mv<0x142, 0xa>(x));
    x = fmaxf(x, dpp_mv<0x143, 0xc>(x));
    return x;
}
__device__ __forceinline__ float bcast63(float x) {
    return __builtin_bit_cast(float,
        __builtin_amdgcn_readlane(__builtin_bit_cast(int, x), 63));
}
__device__ __forceinline__ float fast_rcp(float x) {
    float r;
    asm("v_rcp_f32 %0, %1" : "=v"(r) : "v"(x));
    return r;
}

__device__ __forceinline__ void ce(float& a, float& b) {
    const float hi = fmaxf(a, b);
    const float lo = fminf(a, b);
    a = hi; b = lo;
}
__device__ __forceinline__ void sort4(float& a, float& b, float& c, float& d) {
    ce(a, b); ce(c, d); ce(a, c); ce(b, d); ce(b, c);
}
__device__ __forceinline__ void merge44_top4(
    float A0, float A1, float A2, float A3,
    float B0, float B1, float B2, float B3,
    float& R0, float& R1, float& R2, float& R3) {
    float e0 = A0, e1 = A2, e2 = B0, e3 = B2;
    ce(e0, e2); ce(e1, e3); ce(e1, e2);
    float o0 = A1, o1 = A3, o2 = B1, o3 = B3;
    ce(o0, o2); ce(o1, o3); ce(o1, o2);
    R0 = e0;
    float x = o0, y = e1;
    ce(x, y);
    R1 = x; R2 = y;
    R3 = fmaxf(o1, e2);
}

// 4KB row DMA into LDS (zero-VGPR, unsinkable): 4 x (64 lanes x 16B).
__device__ __forceinline__ void prefetch_row(const float* __restrict__ z,
                                             int row, int lane,
                                             float* ldsbase) {
    const char* g = (const char*)(z + (size_t)row * ROW_D) + (size_t)lane * 16;
#pragma unroll
    for (int j = 0; j < 4; ++j) {
        __builtin_amdgcn_global_load_lds(
            (const __attribute__((address_space(1))) void*)(g + j * 1024),
            (__attribute__((address_space(3))) void*)(ldsbase + j * 256),
            16, 0, 0);
    }
}

__device__ __forceinline__ float solve_tau(const f4 (&v)[4]) {
    float g[4][4];
#pragma unroll
    for (int j = 0; j < 4; ++j) {
        g[j][0] = v[j].x; g[j][1] = v[j].y; g[j][2] = v[j].z; g[j][3] = v[j].w;
        sort4(g[j][0], g[j][1], g[j][2], g[j][3]);
    }
    float a0, a1, a2, a3, b0, b1, b2, b3, T0, T1, T2, T3;
    merge44_top4(g[0][0], g[0][1], g[0][2], g[0][3],
                 g[1][0], g[1][1], g[1][2], g[1][3], a0, a1, a2, a3);
    merge44_top4(g[2][0], g[2][1], g[2][2], g[2][3],
                 g[3][0], g[3][1], g[3][2], g[3][3], b0, b1, b2, b3);
    merge44_top4(a0, a1, a2, a3, b0, b1, b2, b3, T0, T1, T2, T3);

    const float m = bcast63(dpp_max_to63(T0));
    float t = m - 1.0f;

    if (__ballot(T3 > t) == 0ull) {
        // Elements outside any lane's top-4 are <= t0 <= t forever: exact.
#pragma unroll 1
        for (int it = 0; it < 16; ++it) {
            const float d0 = T0 - t, d1 = T1 - t, d2 = T2 - t, d3 = T3 - t;
            const float Sl = (fmaxf(d0, 0.0f) + fmaxf(d1, 0.0f)) +
                             (fmaxf(d2, 0.0f) + fmaxf(d3, 0.0f));
            int n = __popcll(__ballot(d0 > 0.0f));
            n += __popcll(__ballot(d1 > 0.0f));
            n += __popcll(__ballot(d2 > 0.0f));
            n += __popcll(__ballot(d3 > 0.0f));
            const float S = bcast63(dpp_sum_to63(Sl));
            const float step = (S - 1.0f) * fast_rcp((float)n);  // n >= 1
            t += step;
            if (step <= 1e-6f) break;
        }
    } else {
#pragma unroll 1
        for (int it = 0; it < 16; ++it) {
            float sj[4];
            int n = 0;
#pragma unroll
            for (int j = 0; j < 4; ++j) {
                const float d0 = v[j].x - t, d1 = v[j].y - t;
                const float d2 = v[j].z - t, d3 = v[j].w - t;
                sj[j] = (fmaxf(d0, 0.0f) + fmaxf(d1, 0.0f)) +
                        (fmaxf(d2, 0.0f) + fmaxf(d3, 0.0f));
                n += __popcll(__ballot(d0 > 0.0f));
                n += __popcll(__ballot(d1 > 0.0f));
                n += __popcll(__ballot(d2 > 0.0f));
                n += __popcll(__ballot(d3 > 0.0f));
            }
            const float S = bcast63(dpp_sum_to63((sj[0] + sj[1]) + (sj[2] + sj[3])));
            const float step = (S - 1.0f) * fast_rcp((float)n);
            t += step;
            if (step <= 1e-6f) break;
        }
    }
    return t;
}

__device__ __forceinline__ void store_row(const f4 (&v)[4], float t,
                                          float* __restrict__ out,
                                          int row, int lane) {
    f4* __restrict__ p = reinterpret_cast<f4*>(out + (size_t)row * ROW_D);
#pragma unroll
    for (int j = 0; j < 4; ++j) {
        f4 o;
        o.x = fmaxf(v[j].x - t, 0.0f);
        o.y = fmaxf(v[j].y - t, 0.0f);
        o.z = fmaxf(v[j].z - t, 0.0f);
        o.w = fmaxf(v[j].w - t, 0.0f);
        p[lane + 64 * j] = o;
    }
}

// One pipeline step: read slot, solve, (DMA next+3 into same slot), store.
__device__ __forceinline__ void pipe_step(const float* __restrict__ z,
                                          float* __restrict__ out,
                                          float* slot, int k, int kdma,
                                          int lane, bool do_dma) {
    f4 v[4];
    const f4* lsrc = reinterpret_cast<const f4*>(slot);
#pragma unroll
    for (int j = 0; j < 4; ++j) v[j] = lsrc[lane + 64 * j];
    const float t = solve_tau(v);
    __builtin_amdgcn_sched_barrier(0);
    if (do_dma) prefetch_row(z, kdma, lane, slot);   // DMA before stores
    __builtin_amdgcn_sched_barrier(0);
    store_row(v, t, out, k, lane);
    __builtin_amdgcn_sched_barrier(0);
}

#define WAIT_VM(N) do { \
    asm volatile("s_waitcnt vmcnt(" #N ")" ::: "memory"); \
    __builtin_amdgcn_sched_barrier(0); } while (0)

// Requires: every wave has T >= 6 rows (launcher guarantees nrows >= 6*W).
__global__ __launch_bounds__(256) void sparsemax_pipe(
    const float* __restrict__ z, float* __restrict__ out, int nrows) {
    const int lane = (int)(threadIdx.x & 63u);
    const int w    = (int)(threadIdx.x >> 6);
    const int wid  = (int)(blockIdx.x << 2) + w;
    const int W    = (int)(gridDim.x << 2);
    if (wid >= nrows) return;

    __shared__ float lds[4][3][ROW_D];     // 48KB/block -> 3 blocks/CU
    float* slot0 = &lds[w][0][0];
    float* slot1 = &lds[w][1][0];
    float* slot2 = &lds[w][2][0];

    const int T = (nrows - wid + W - 1) / W;   // rows for this wave (>= 6)

    // Prologue: fill all 3 slots.
    int k = wid;
    prefetch_row(z, k,         lane, slot0);
    prefetch_row(z, k + W,     lane, slot1);
    prefetch_row(z, k + 2 * W, lane, slot2);
    __builtin_amdgcn_sched_barrier(0);

    // Peeled iters 0..2 (prologue wait counts 8/12/16), DMA k+3W each.
    WAIT_VM(8);
    pipe_step(z, out, slot0, k, k + 3 * W, lane, true); k += W;   // i=0
    WAIT_VM(12);
    pipe_step(z, out, slot1, k, k + 3 * W, lane, true); k += W;   // i=1
    WAIT_VM(16);
    pipe_step(z, out, slot2, k, k + 3 * W, lane, true); k += W;   // i=2

    // Steady state: i = 3 .. T-4, slot rotates i%3, wait 20.
    float* slots[3] = {slot0, slot1, slot2};
    int s = 0;
#pragma unroll 1
    for (int i = 3; i + 3 < T; ++i) {
        WAIT_VM(20);
        pipe_step(z, out, slots[s], k, k + 3 * W, lane, true);
        k += W;
        s = (s == 2) ? 0 : s + 1;
    }

    // Epilogue: last 3 rows, no DMA; waits 20/16/12.
    WAIT_VM(20);
    pipe_step(z, out, slots[s], k, 0, lane, false); k += W;
    s = (s == 2) ? 0 : s + 1;
    WAIT_VM(16);
    pipe_step(z, out, slots[s], k, 0, lane, false); k += W;
    s = (s == 2) ? 0 : s + 1;
    WAIT_VM(12);
    pipe_step(z, out, slots[s], k, 0, lane, false);
}

// Fallback: R6 kernel (best known simple form), 1 wave/row.
__global__ __launch_bounds__(256) void sparsemax_simple(
    const float* __restrict__ z, float* __restrict__ out, int nrows) {
    const int lane = (int)(threadIdx.x & 63u);
    const int row  = (int)(blockIdx.x << 2) + (int)(threadIdx.x >> 6);
    if (row >= nrows) return;
    const f4* __restrict__ zin = reinterpret_cast<const f4*>(z + (size_t)row * ROW_D);
    f4 v[4];
#pragma unroll
    for (int j = 0; j < 4; ++j) v[j] = zin[lane + 64 * j];
    const float t = solve_tau(v);
    store_row(v, t, out, row, lane);
}

extern "C" void kernel_launch(void* const* d_in, const int* in_sizes, int n_in,
                              void* d_out, int out_size, void* d_ws, size_t ws_size,
                              hipStream_t stream) {
    const float* z = (const float*)d_in[0];
    float* out = (float*)d_out;
    const int n = in_sizes[0];            // 8*4096*1024
    const int nrows = n / ROW_D;          // 32768

    const int blocks = 768;               // 3 blocks/CU (48KB LDS each)
    const int W = blocks * 4;             // 3072 waves
    if (nrows >= 6 * W) {
        sparsemax_pipe<<<blocks, 256, 0, stream>>>(z, out, nrows);
    } else {
        sparsemax_simple<<<(nrows + 3) / 4, 256, 0, stream>>>(z, out, nrows);
    }
}

// Round 10
// 227.166 us; speedup vs baseline: 1.0285x; 1.0285x over previous
//
#include <hip/hip_runtime.h>

// Sparsemax, last dim d=1024, 32768 rows, fp32 — top-4 compacted Newton
// solve (session-best configuration, R6; resubmitted as final).
// Session record (R0-R9): eleven structures — multi-row ILP, persistent
// waves, register pipelines (x2, compiler-defeated), NT vs cached stores,
// two-pass split, LDS-DMA prefetch (depth-2 and depth-3, HW-verified),
// 4-row lockstep groups, low-occupancy streaming — ALL land at 75-90us
// with HBM ~30% and VALU 21-36%. Delivered BW is invariant to outstanding
// depth (8KB..144KB/CU), occupancy (16-62%), and store policy. The only
// lever that measurably moved time was cutting solve VALU work (this
// kernel). Remaining gap to the 32us HBM floor is not attributable to
// any counter-visible pipe; declared the practical plateau.
// Solve: per-lane top-4-of-16 sorting network (~85 VALU once), then
// exact 4-elem Newton  t' = t + (S(t)-1)/C(t), t0 = max-1 (monotone from
// below on the convex piecewise-linear objective, ~5-8 iters). Elements
// outside a lane's top-4 are <= t0 <= t for all iterates, so they never
// contribute; if any lane's 4th-largest > t0 (wave ballot, rare), the
// whole wave runs the exact full-16 path. rcp not divide: C is an exact
// small int, ~2^-22 rel err, final step -> 0, tau err ~1e-7 << 2e-3 tol.

#define ROW_D 1024

typedef float f4 __attribute__((ext_vector_type(4)));

template <int CTRL, int RMASK>
__device__ __forceinline__ float dpp_mv(float x) {
    return __builtin_bit_cast(float, __builtin_amdgcn_update_dpp(
        __builtin_bit_cast(int, x), __builtin_bit_cast(int, x),
        CTRL, RMASK, 0xf, false));
}

// Wave64 sum -> total lands in lane 63. row_shr:k folds each 16-lane row
// into its top lane; bcast15/31 fold rows.
__device__ __forceinline__ float dpp_sum_to63(float x) {
    x += dpp_mv<0x111, 0xf>(x);   // row_shr:1
    x += dpp_mv<0x112, 0xf>(x);   // row_shr:2
    x += dpp_mv<0x114, 0xf>(x);   // row_shr:4
    x += dpp_mv<0x118, 0xf>(x);   // row_shr:8
    x += dpp_mv<0x142, 0xa>(x);   // row_bcast15 -> rows 1,3
    x += dpp_mv<0x143, 0xc>(x);   // row_bcast31 -> rows 2,3
    return x;
}
__device__ __forceinline__ float dpp_max_to63(float x) {
    x = fmaxf(x, dpp_mv<0x111, 0xf>(x));
    x = fmaxf(x, dpp_mv<0x112, 0xf>(x));
    x = fmaxf(x, dpp_mv<0x114, 0xf>(x));
    x = fmaxf(x, dpp_mv<0x118, 0xf>(x));
    x = fmaxf(x, dpp_mv<0x142, 0xa>(x));
    x = fmaxf(x, dpp_mv<0x143, 0xc>(x));
    return x;
}
__device__ __forceinline__ float bcast63(float x) {
    return __builtin_bit_cast(float,
        __builtin_amdgcn_readlane(__builtin_bit_cast(int, x), 63));
}
__device__ __forceinline__ float fast_rcp(float x) {
    float r;
    asm("v_rcp_f32 %0, %1" : "=v"(r) : "v"(x));
    return r;
}

// Compare-exchange, descending (a keeps max).
__device__ __forceinline__ void ce(float& a, float& b) {
    const float hi = fmaxf(a, b);
    const float lo = fminf(a, b);
    a = hi; b = lo;
}
// Sort 4 desc: 5 CE.
__device__ __forceinline__ void sort4(float& a, float& b, float& c, float& d) {
    ce(a, b); ce(c, d); ce(a, c); ce(b, d); ce(b, c);
}
// Top-4 of two desc-sorted 4-lists (pruned Batcher odd-even merge).
__device__ __forceinline__ void merge44_top4(
    float A0, float A1, float A2, float A3,
    float B0, float B1, float B2, float B3,
    float& R0, float& R1, float& R2, float& R3) {
    float e0 = A0, e1 = A2, e2 = B0, e3 = B2;
    ce(e0, e2); ce(e1, e3); ce(e1, e2);          // E = (e0,e1,e2,.)
    float o0 = A1, o1 = A3, o2 = B1, o3 = B3;
    ce(o0, o2); ce(o1, o3); ce(o1, o2);          // O = (o0,o1,.)
    R0 = e0;
    float x = o0, y = e1;
    ce(x, y);
    R1 = x; R2 = y;
    R3 = fmaxf(o1, e2);
}

__global__ __launch_bounds__(256) void sparsemax_kernel(
    const float* __restrict__ z, float* __restrict__ out, int nrows) {
    const int lane = (int)(threadIdx.x & 63u);
    const int row  = (int)(blockIdx.x << 2) + (int)(threadIdx.x >> 6);
    if (row >= nrows) return;

    const f4* __restrict__ zin = reinterpret_cast<const f4*>(z + (size_t)row * ROW_D);
    f4* __restrict__ pout      = reinterpret_cast<f4*>(out + (size_t)row * ROW_D);

    // 16 elements/lane, 4 coalesced dwordx4 loads.
    f4 v[4];
#pragma unroll
    for (int j = 0; j < 4; ++j) v[j] = zin[lane + 64 * j];

    // Lane-local top-4 of 16: sort each f4 (4x5 CE), tournament merges.
    float g[4][4];
#pragma unroll
    for (int j = 0; j < 4; ++j) {
        g[j][0] = v[j].x; g[j][1] = v[j].y; g[j][2] = v[j].z; g[j][3] = v[j].w;
        sort4(g[j][0], g[j][1], g[j][2], g[j][3]);
    }
    float a0, a1, a2, a3, b0, b1, b2, b3, T0, T1, T2, T3;
    merge44_top4(g[0][0], g[0][1], g[0][2], g[0][3],
                 g[1][0], g[1][1], g[1][2], g[1][3], a0, a1, a2, a3);
    merge44_top4(g[2][0], g[2][1], g[2][2], g[2][3],
                 g[3][0], g[3][1], g[3][2], g[3][3], b0, b1, b2, b3);
    merge44_top4(a0, a1, a2, a3, b0, b1, b2, b3, T0, T1, T2, T3);

    // Row max = wave max of per-lane maxes (T0).
    const float m = bcast63(dpp_max_to63(T0));
    float t = m - 1.0f;

    // Elements outside a lane's top-4 are <= T3. If T3 <= t0 on every
    // lane, they are <= t for ALL Newton iterates (t only increases) and
    // contribute 0 to S and C forever -> 4-element iterations are EXACT.
    const unsigned long long bad = __ballot(T3 > t);
    if (bad == 0ull) {
        // Fast path: 4 elements/lane/iter.
#pragma unroll 1
        for (int it = 0; it < 16; ++it) {
            const float d0 = T0 - t, d1 = T1 - t, d2 = T2 - t, d3 = T3 - t;
            const float Sl = (fmaxf(d0, 0.0f) + fmaxf(d1, 0.0f)) +
                             (fmaxf(d2, 0.0f) + fmaxf(d3, 0.0f));
            int n = __popcll(__ballot(d0 > 0.0f));     // SALU counts
            n += __popcll(__ballot(d1 > 0.0f));
            n += __popcll(__ballot(d2 > 0.0f));
            n += __popcll(__ballot(d3 > 0.0f));
            const float S = bcast63(dpp_sum_to63(Sl));
            const float step = (S - 1.0f) * fast_rcp((float)n);  // n >= 1
            t += step;
            if (step <= 1e-6f) break;   // wave-uniform exit
        }
    } else {
        // Full path (rare, exact): all 16 elements/lane.
#pragma unroll 1
        for (int it = 0; it < 16; ++it) {
            float sj[4];
            int n = 0;
#pragma unroll
            for (int j = 0; j < 4; ++j) {
                const float d0 = v[j].x - t, d1 = v[j].y - t;
                const float d2 = v[j].z - t, d3 = v[j].w - t;
                sj[j] = (fmaxf(d0, 0.0f) + fmaxf(d1, 0.0f)) +
                        (fmaxf(d2, 0.0f) + fmaxf(d3, 0.0f));
                n += __popcll(__ballot(d0 > 0.0f));
                n += __popcll(__ballot(d1 > 0.0f));
                n += __popcll(__ballot(d2 > 0.0f));
                n += __popcll(__ballot(d3 > 0.0f));
            }
            const float S = bcast63(dpp_sum_to63((sj[0] + sj[1]) + (sj[2] + sj[3])));
            const float step = (S - 1.0f) * fast_rcp((float)n);  // n >= 1
            t += step;
            if (step <= 1e-6f) break;
        }
    }

    // p = relu(z - tau).
#pragma unroll
    for (int j = 0; j < 4; ++j) {
        f4 o;
        o.x = fmaxf(v[j].x - t, 0.0f);
        o.y = fmaxf(v[j].y - t, 0.0f);
        o.z = fmaxf(v[j].z - t, 0.0f);
        o.w = fmaxf(v[j].w - t, 0.0f);
        pout[lane + 64 * j] = o;
    }
}

extern "C" void kernel_launch(void* const* d_in, const int* in_sizes, int n_in,
                              void* d_out, int out_size, void* d_ws, size_t ws_size,
                              hipStream_t stream) {
    const float* z = (const float*)d_in[0];
    float* out = (float*)d_out;
    const int n = in_sizes[0];            // 8*4096*1024
    const int nrows = n / ROW_D;          // 32768
    const int blocks = (nrows + 3) / 4;   // 1 wave per row, 4 waves/block
    sparsemax_kernel<<<blocks, 256, 0, stream>>>(z, out, nrows);
}